// Round 13
// baseline (150.564 us; speedup 1.0000x reference)
//
#include <hip/hip_runtime.h>

#define BB 8
#define SS 2048
#define EE 512
#define HD 64
#define CHUNK 256
#define KT 64
#define NCH 8          // max chunks per 64-row q-block (combine layout)
#define PST 72         // P LDS row stride (elems)
#define TST 72         // K/V LDS row stride (elems)
#define XRS 40         // qkv LDS row stride within kb chunk
#define XKB 1280       // qkv LDS kb-chunk stride (32 rows * XRS)
#define NITEMS 576     // 8 b * 72 (128-row q-blocks x ceil((Q+1)/2) chunks)
#define NPACK 12       // pack blocks (3*E*64 = 12*8192)
#define MAGIC 0x13572468

typedef __attribute__((ext_vector_type(8))) short bf16x8;
typedef __attribute__((ext_vector_type(4))) float f32x4;

static __device__ __forceinline__ unsigned short f2bf(float f) {
    unsigned u = __builtin_bit_cast(unsigned, f);
    u = (u + 0x7fffu + ((u >> 16) & 1u)) >> 16;  // RNE
    return (unsigned short)u;
}
static __device__ __forceinline__ unsigned short f2bf_trunc(float f) {
    return (unsigned short)(__builtin_bit_cast(unsigned, f) >> 16);
}
static __device__ __forceinline__ float bf2f(unsigned short h) {
    unsigned u = ((unsigned)h) << 16;
    return __builtin_bit_cast(float, u);
}

// Fused pack+QKV, one dispatch. Blocks 0..11: pack W (fp32->bf16 B-frag
// layout, Wq pre-scaled); release flags. Blocks 12..523: stage x first
// (latency-heavy, Wt-independent), THEN spin on flags (pack hidden), acquire,
// MFMA. Deadlock-free: 524 blocks <= 768 resident slots.
__global__ __launch_bounds__(256) void qkv_kernel(
    const float* __restrict__ x,            // [B*S, E] fp32
    const float* __restrict__ Wq, const float* __restrict__ Wk, const float* __restrict__ Wv,
    unsigned short* __restrict__ Wt,        // packed bf16, 3*E*64
    unsigned short* __restrict__ q,
    unsigned short* __restrict__ k,
    unsigned short* __restrict__ vT,
    int* __restrict__ flags) {              // [NPACK], poison != MAGIC at entry
    const int tid = threadIdx.x;
    const int bid = blockIdx.x;

    if (bid < NPACK) {
        // ---- pack: 8192 elems per block ----
        for (int i = 0; i < 32; ++i) {
            int tg = bid * 8192 + i * 256 + tid;
            int w_idx = tg / (EE * HD);
            int rem = tg % (EE * HD);
            int kk = rem / HD, n = rem % HD;
            const float* Wsrc = (w_idx == 0) ? Wq : ((w_idx == 1) ? Wk : Wv);
            float val = Wsrc[kk * HD + n];
            if (w_idx == 0) val *= 0.125f;  // fold scores scale into q
            int kb = kk >> 5, kr = kk & 31, quad = kr >> 3, j = kr & 7;
            int t = n >> 4, c = n & 15;
            int lane = quad * 16 + c;
            Wt[w_idx * (EE * HD) + ((kb * 4 + t) * 64 + lane) * 8 + j] = f2bf(val);
        }
        __syncthreads();                 // all stores issued & drained
        if (tid == 0) {
            __threadfence();             // release Wt
            atomicExch(&flags[bid], MAGIC);
        }
        return;
    }

    // ---- qkv: 512 blocks, 32 rows each ----
    __shared__ __align__(16) unsigned short Xs[16 * XKB];  // 40 KB
    const int lane = tid & 63;
    const int t = tid >> 6;  // wave = output col-tile 0..3
    const int c = lane & 15, quad = lane >> 4;
    const int r0 = (bid - NPACK) * 32;

    // stage 32 rows x 512 cols fp32 -> bf16 LDS, kb-major (Wt-independent)
    const float* xt = x + (size_t)r0 * EE;
#pragma unroll
    for (int i = 0; i < 16; ++i) {
        int fi = i * 256 + tid;  // float4 index 0..4095
        int e4 = fi * 4;
        float4 v4 = *(const float4*)(xt + e4);
        int row = e4 >> 9, col = e4 & 511;
        int kb = col >> 5, cc = col & 31;
        ushort4 pk;
        pk.x = f2bf(v4.x); pk.y = f2bf(v4.y); pk.z = f2bf(v4.z); pk.w = f2bf(v4.w);
        *(ushort4*)(&Xs[kb * XKB + row * XRS + cc]) = pk;
    }
    // wait for pack (usually already done — hidden behind staging)
    if (tid == 0) {
        for (int i = 0; i < NPACK; ++i)
            while (atomicOr(&flags[i], 0) != MAGIC) __builtin_amdgcn_s_sleep(2);
    }
    __syncthreads();
    __threadfence();  // acquire Wt (cold: x already in LDS, L2 barely warm)

    f32x4 acc[2][3];
#pragma unroll
    for (int rt = 0; rt < 2; ++rt)
        for (int m = 0; m < 3; ++m) acc[rt][m] = (f32x4){0.f, 0.f, 0.f, 0.f};

    const unsigned short* wbase0 = Wt + t * 512 + lane * 8;
#pragma unroll
    for (int kb = 0; kb < EE / 32; ++kb) {
        const unsigned short* wb = wbase0 + kb * 2048;
        bf16x8 bfrag[3];
#pragma unroll
        for (int m = 0; m < 3; ++m) bfrag[m] = *(const bf16x8*)(wb + m * (EE * HD));
#pragma unroll
        for (int rt = 0; rt < 2; ++rt) {
            bf16x8 afrag = *(const bf16x8*)(&Xs[kb * XKB + (rt * 16 + c) * XRS + quad * 8]);
#pragma unroll
            for (int m = 0; m < 3; ++m)
                acc[rt][m] = __builtin_amdgcn_mfma_f32_16x16x32_bf16(afrag, bfrag[m], acc[rt][m], 0, 0, 0);
        }
    }

    const int col = t * 16 + c;
#pragma unroll
    for (int rt = 0; rt < 2; ++rt) {
        const int rb = r0 + rt * 16;
        for (int r = 0; r < 4; ++r) {
            int row = rb + quad * 4 + r;
            q[(size_t)row * HD + col] = f2bf(acc[rt][0][r]);
            k[(size_t)row * HD + col] = f2bf(acc[rt][1][r]);
        }
        int row = rb + quad * 4;
        int b_ = row >> 11, sb = row & (SS - 1);
        ushort4 pk;
        pk.x = f2bf(acc[rt][2][0]); pk.y = f2bf(acc[rt][2][1]);
        pk.z = f2bf(acc[rt][2][2]); pk.w = f2bf(acc[rt][2][3]);
        *(ushort4*)(vT + ((size_t)b_ * HD + col) * SS + sb) = pk;
    }
}

// Split-K attention (R12-proven, unchanged): 128-row q-items, direct blockIdx
// mapping. Item = (b, Q, cx): 128 q-rows x one 256-key chunk; each wave owns
// 32 rows (2 row-tiles).
__global__ __launch_bounds__(256, 3) void attn_kernel(
    const unsigned short* __restrict__ q,
    const unsigned short* __restrict__ k,
    const unsigned short* __restrict__ vT,
    const int* __restrict__ mask,
    unsigned short* __restrict__ po,   // [B][32 qb][NCH][64 rows][64 d] bf16
    float* __restrict__ pl,            // [B][32 qb][NCH][64 rows] fp32
    float* __restrict__ out) {
    __shared__ __align__(16) unsigned short Ks[2][64 * TST];
    __shared__ __align__(16) unsigned short Vs[2][64 * TST];
    __shared__ __align__(16) unsigned short Ps[4][16 * PST];
    const int tid = threadIdx.x;
    const int lane = tid & 63, wave = tid >> 6;
    const int c = lane & 15, quad = lane >> 4;

    int t = NITEMS - 1 - blockIdx.x;       // big items first (low blockIdx)
    const int b_ = t / 72;
    int r = t % 72;
    int g = 0;
    while ((g + 1) * (g + 2) <= r) ++g;    // group: Q in {2g,2g+1}, nch=g+1
    int rr = r - g * (g + 1);
    const int Q = 2 * g + rr / (g + 1);
    const int cx = rr % (g + 1);
    const int kstart = cx * CHUNK;
    const int kend = min(kstart + CHUNK, Q * 128 + 128);
    const int ntiles = (kend - kstart) >> 6;   // 1..4 whole tiles
    const int nch_active = Q / 2 + 1;
    const int r0 = Q * 128 + wave * 32;        // this wave's first row

    const unsigned short* qb_p = q + (size_t)b_ * SS * HD;
    const unsigned short* kb_p = k + (size_t)b_ * SS * HD;
    const unsigned short* vb = vT + (size_t)b_ * HD * SS;
    const int* mb = mask + b_ * SS;

    bf16x8 aq[2][2];
#pragma unroll
    for (int rt = 0; rt < 2; ++rt) {
        const unsigned short* qrow = qb_p + (size_t)(r0 + rt * 16 + c) * HD + quad * 8;
        aq[rt][0] = *(const bf16x8*)(qrow);
        aq[rt][1] = *(const bf16x8*)(qrow + 32);
    }

    f32x4 o[2][4];
    float l_i[2][4];
#pragma unroll
    for (int rt = 0; rt < 2; ++rt)
        for (int tt = 0; tt < 4; ++tt) {
            o[rt][tt] = (f32x4){0.f, 0.f, 0.f, 0.f};
            l_i[rt][tt] = 0.f;
        }

    auto stage = [&](int buf, int k0) {
        const unsigned short* ksrc = kb_p + (size_t)k0 * HD;
        unsigned short* kd = &Ks[buf][0];
        unsigned short* vd = &Vs[buf][0];
#pragma unroll
        for (int rnd = 0; rnd < 2; ++rnd) {
            int e = (rnd * 256 + tid) * 8;
            int krow = e >> 6, kcol = e & 63;
            *(bf16x8*)(kd + krow * TST + kcol) = *(const bf16x8*)(ksrc + e);
            int t8 = rnd * 256 + tid;
            int vr = t8 >> 3, vc = (t8 & 7) * 8;
            *(bf16x8*)(vd + vr * TST + vc) = *(const bf16x8*)(vb + (size_t)vr * SS + k0 + vc);
        }
    };

    stage(0, kstart);
    for (int kt = 0; kt < ntiles; ++kt) {
        __syncthreads();
        const unsigned short* ks = &Ks[kt & 1][0];
        const unsigned short* vs = &Vs[kt & 1][0];
        const int k0 = kstart + kt * KT;
        bf16x8 kf[4][2];
#pragma unroll
        for (int kg = 0; kg < 4; ++kg) {
            kf[kg][0] = *(const bf16x8*)(ks + (kg * 16 + c) * TST + quad * 8);
            kf[kg][1] = *(const bf16x8*)(ks + (kg * 16 + c) * TST + 32 + quad * 8);
        }
        if (kt + 1 < ntiles) stage((kt + 1) & 1, k0 + KT);
#pragma unroll
        for (int rt = 0; rt < 2; ++rt) {
            const int rbase = r0 + rt * 16;
            const bool fullc = (k0 + KT <= rbase);
            float p[4][4];
#pragma unroll
            for (int kg = 0; kg < 4; ++kg) {
                f32x4 accs = (f32x4){0.f, 0.f, 0.f, 0.f};
                accs = __builtin_amdgcn_mfma_f32_16x16x32_bf16(aq[rt][0], kf[kg][0], accs, 0, 0, 0);
                accs = __builtin_amdgcn_mfma_f32_16x16x32_bf16(aq[rt][1], kf[kg][1], accs, 0, 0, 0);
                int key = k0 + kg * 16 + c;
                bool mk = (mb[key] != 0);
                for (int rr2 = 0; rr2 < 4; ++rr2) {
                    int row = rbase + quad * 4 + rr2;
                    bool keep = mk && (fullc || key <= row);
                    float e = __expf(fminf(accs[rr2], 80.f));  // scale folded into q
                    float pe = keep ? e : 0.f;
                    p[kg][rr2] = pe;
                    l_i[rt][rr2] += pe;
                }
            }
            unsigned short* pbuf = &Ps[wave][0];
#pragma unroll
            for (int kg = 0; kg < 4; ++kg)
                for (int rr2 = 0; rr2 < 4; ++rr2)
                    pbuf[(quad * 4 + rr2) * PST + kg * 16 + c] = f2bf_trunc(p[kg][rr2]);
            bf16x8 pa0 = *(const bf16x8*)(pbuf + c * PST + quad * 8);
            bf16x8 pa1 = *(const bf16x8*)(pbuf + c * PST + 32 + quad * 8);
#pragma unroll
            for (int tt = 0; tt < 4; ++tt) {
                bf16x8 bv0 = *(const bf16x8*)(vs + (tt * 16 + c) * TST + quad * 8);
                bf16x8 bv1 = *(const bf16x8*)(vs + (tt * 16 + c) * TST + 32 + quad * 8);
                o[rt][tt] = __builtin_amdgcn_mfma_f32_16x16x32_bf16(pa0, bv0, o[rt][tt], 0, 0, 0);
                o[rt][tt] = __builtin_amdgcn_mfma_f32_16x16x32_bf16(pa1, bv1, o[rt][tt], 0, 0, 0);
            }
        }
    }

#pragma unroll
    for (int rt = 0; rt < 2; ++rt)
        for (int rr2 = 0; rr2 < 4; ++rr2) {
            float s = l_i[rt][rr2];
            s += __shfl_xor(s, 1);
            s += __shfl_xor(s, 2);
            s += __shfl_xor(s, 4);
            s += __shfl_xor(s, 8);
            l_i[rt][rr2] = s;
        }

    if (nch_active == 1) {
        // rows < 256: sole chunk, final output directly
#pragma unroll
        for (int rt = 0; rt < 2; ++rt)
            for (int rr2 = 0; rr2 < 4; ++rr2) {
                int row = r0 + rt * 16 + quad * 4 + rr2;
                float l = l_i[rt][rr2];
                float inv = (l > 0.f) ? 1.f / l : 0.f;
                for (int tt = 0; tt < 4; ++tt)
                    out[((size_t)b_ * SS + row) * HD + tt * 16 + c] = o[rt][tt][rr2] * inv;
            }
        return;
    }

#pragma unroll
    for (int rt = 0; rt < 2; ++rt)
        for (int rr2 = 0; rr2 < 4; ++rr2) {
            int row_abs = r0 + rt * 16 + quad * 4 + rr2;
            int qb_i = row_abs >> 6, rl = row_abs & 63;
            size_t base = (size_t)(b_ * 32 + qb_i) * NCH + cx;
            float l = l_i[rt][rr2];
            float inv = (l > 0.f) ? 1.f / l : 0.f;
            for (int tt = 0; tt < 4; ++tt)
                po[base * 4096 + (size_t)rl * 64 + tt * 16 + c] = f2bf(o[rt][tt][rr2] * inv);
            if (c == 0) pl[base * 64 + rl] = l;
        }
}

// Combine rows >= 256 only: out = sum_c l_c * o_c / sum_c l_c.
__global__ __launch_bounds__(256) void combine_kernel(
    const unsigned short* __restrict__ po,
    const float* __restrict__ pl,
    float* __restrict__ out) {
    int t = blockIdx.x * 256 + threadIdx.x;
    if (t >= BB * (SS - 256) * HD) return;
    int d = t & 63;
    int rg = t >> 6;
    int b_ = rg / (SS - 256);
    int row = 256 + rg % (SS - 256);
    int qb = row >> 6, rl = row & 63;
    int nch = row / CHUNK + 1;
    size_t base = (size_t)(b_ * 32 + qb) * NCH;
    float L = 0.f, acc = 0.f;
    for (int c = 0; c < nch; ++c) {
        float l = pl[(base + c) * 64 + rl];
        L += l;
        acc += l * bf2f(po[(base + c) * 4096 + (size_t)rl * 64 + d]);
    }
    out[((size_t)b_ * SS + row) * HD + d] = (L > 0.f) ? acc / L : 0.f;
}

extern "C" void kernel_launch(void* const* d_in, const int* in_sizes, int n_in,
                              void* d_out, int out_size, void* d_ws, size_t ws_size,
                              hipStream_t stream) {
    const float* x = (const float*)d_in[0];
    const float* Wq = (const float*)d_in[1];
    const float* Wk = (const float*)d_in[2];
    const float* Wv = (const float*)d_in[3];
    const int* mask = (const int*)d_in[4];
    float* out = (float*)d_out;

    // ws: Wt[98304] | q,k,vT[3x1048576] bf16 | po bf16 | pl fp32 | flags[NPACK]
    unsigned short* ws = (unsigned short*)d_ws;
    unsigned short* Wt = ws;
    unsigned short* q = Wt + 3 * EE * HD;
    unsigned short* kk = q + (size_t)BB * SS * HD;
    unsigned short* vT = kk + (size_t)BB * SS * HD;
    unsigned short* po = vT + (size_t)BB * SS * HD;
    float* pl = (float*)(po + (size_t)BB * 32 * NCH * 4096);
    int* flags = (int*)(pl + (size_t)BB * 32 * NCH * 64);

    qkv_kernel<<<dim3(NPACK + BB * SS / 32), dim3(256), 0, stream>>>(x, Wq, Wk, Wv, Wt, q, kk, vT, flags);
    attn_kernel<<<dim3(NITEMS), dim3(256), 0, stream>>>(q, kk, vT, mask, po, pl, out);
    combine_kernel<<<dim3((BB * (SS - 256) * HD + 255) / 256), dim3(256), 0, stream>>>(po, pl, out);
}

// Round 14
// 149.501 us; speedup vs baseline: 1.0071x; 1.0071x over previous
//
#include <hip/hip_runtime.h>

#define BB 8
#define SS 2048
#define EE 512
#define HD 64
#define CHUNK 256
#define KT 64
#define NCH 8          // max chunks per 64-row q-block (combine layout)
#define PST 72         // P LDS row stride (elems)
#define TST 72         // K/V LDS row stride (elems)
#define XRS 40         // qkv LDS row stride within kb chunk
#define XKB 1280       // qkv LDS kb-chunk stride (32 rows * XRS)
#define NITEMS 576     // 8 b * 72 (128-row q-blocks x ceil((Q+1)/2) chunks)
#define NPACK 12       // pack blocks (3*E*64 = 12*8192)
#define MAGIC 0x13572468

typedef __attribute__((ext_vector_type(8))) short bf16x8;
typedef __attribute__((ext_vector_type(4))) float f32x4;

static __device__ __forceinline__ unsigned short f2bf(float f) {
    unsigned u = __builtin_bit_cast(unsigned, f);
    u = (u + 0x7fffu + ((u >> 16) & 1u)) >> 16;  // RNE
    return (unsigned short)u;
}
static __device__ __forceinline__ unsigned short f2bf_trunc(float f) {
    return (unsigned short)(__builtin_bit_cast(unsigned, f) >> 16);
}
static __device__ __forceinline__ float bf2f(unsigned short h) {
    unsigned u = ((unsigned)h) << 16;
    return __builtin_bit_cast(float, u);
}

// Fused pack+QKV, one dispatch. Blocks 0..11: pack W; release via atomicExch.
// Blocks 12..523: stage x first (Wt-independent), then wait on flags with
// COHERENT READ-ONLY loads (no RMW -> no cacheline ownership contention; the
// R13 regression was 512 blocks RMW-polling the same line). Deadlock-free:
// 524 blocks <= resident capacity, pack blocks always run.
__global__ __launch_bounds__(256) void qkv_kernel(
    const float* __restrict__ x,            // [B*S, E] fp32
    const float* __restrict__ Wq, const float* __restrict__ Wk, const float* __restrict__ Wv,
    unsigned short* __restrict__ Wt,        // packed bf16, 3*E*64
    unsigned short* __restrict__ q,
    unsigned short* __restrict__ k,
    unsigned short* __restrict__ vT,
    int* __restrict__ flags) {              // [NPACK], poison != MAGIC at entry
    const int tid = threadIdx.x;
    const int bid = blockIdx.x;

    if (bid < NPACK) {
        // ---- pack: 8192 elems per block; Wq pre-scaled by HEAD^-0.5 ----
        for (int i = 0; i < 32; ++i) {
            int tg = bid * 8192 + i * 256 + tid;
            int w_idx = tg / (EE * HD);
            int rem = tg % (EE * HD);
            int kk = rem / HD, n = rem % HD;
            const float* Wsrc = (w_idx == 0) ? Wq : ((w_idx == 1) ? Wk : Wv);
            float val = Wsrc[kk * HD + n];
            if (w_idx == 0) val *= 0.125f;  // fold scores scale into q
            int kb = kk >> 5, kr = kk & 31, quad = kr >> 3, j = kr & 7;
            int t = n >> 4, c = n & 15;
            int lane = quad * 16 + c;
            Wt[w_idx * (EE * HD) + ((kb * 4 + t) * 64 + lane) * 8 + j] = f2bf(val);
        }
        __syncthreads();                 // all stores issued & drained
        if (tid == 0) {
            __threadfence();             // release Wt
            atomicExch(&flags[bid], MAGIC);
        }
        return;
    }

    // ---- qkv: 512 blocks, 32 rows each ----
    __shared__ __align__(16) unsigned short Xs[16 * XKB];  // 40 KB
    const int lane = tid & 63;
    const int t = tid >> 6;  // wave = output col-tile 0..3
    const int c = lane & 15, quad = lane >> 4;
    const int r0 = (bid - NPACK) * 32;

    // stage 32 rows x 512 cols fp32 -> bf16 LDS, kb-major (Wt-independent)
    const float* xt = x + (size_t)r0 * EE;
#pragma unroll
    for (int i = 0; i < 16; ++i) {
        int fi = i * 256 + tid;  // float4 index 0..4095
        int e4 = fi * 4;
        float4 v4 = *(const float4*)(xt + e4);
        int row = e4 >> 9, col = e4 & 511;
        int kb = col >> 5, cc = col & 31;
        ushort4 pk;
        pk.x = f2bf(v4.x); pk.y = f2bf(v4.y); pk.z = f2bf(v4.z); pk.w = f2bf(v4.w);
        *(ushort4*)(&Xs[kb * XKB + row * XRS + cc]) = pk;
    }
    // wait for pack: coherent read-only polling (no RMW ping-pong)
    if (tid == 0) {
        for (int i = 0; i < NPACK; ++i)
            while (__hip_atomic_load(&flags[i], __ATOMIC_RELAXED,
                                     __HIP_MEMORY_SCOPE_AGENT) != MAGIC)
                __builtin_amdgcn_s_sleep(8);
    }
    __syncthreads();
    __threadfence();  // acquire Wt

    f32x4 acc[2][3];
#pragma unroll
    for (int rt = 0; rt < 2; ++rt)
        for (int m = 0; m < 3; ++m) acc[rt][m] = (f32x4){0.f, 0.f, 0.f, 0.f};

    const unsigned short* wbase0 = Wt + t * 512 + lane * 8;
#pragma unroll
    for (int kb = 0; kb < EE / 32; ++kb) {
        const unsigned short* wb = wbase0 + kb * 2048;
        bf16x8 bfrag[3];
#pragma unroll
        for (int m = 0; m < 3; ++m) bfrag[m] = *(const bf16x8*)(wb + m * (EE * HD));
#pragma unroll
        for (int rt = 0; rt < 2; ++rt) {
            bf16x8 afrag = *(const bf16x8*)(&Xs[kb * XKB + (rt * 16 + c) * XRS + quad * 8]);
#pragma unroll
            for (int m = 0; m < 3; ++m)
                acc[rt][m] = __builtin_amdgcn_mfma_f32_16x16x32_bf16(afrag, bfrag[m], acc[rt][m], 0, 0, 0);
        }
    }

    const int col = t * 16 + c;
#pragma unroll
    for (int rt = 0; rt < 2; ++rt) {
        const int rb = r0 + rt * 16;
        for (int r = 0; r < 4; ++r) {
            int row = rb + quad * 4 + r;
            q[(size_t)row * HD + col] = f2bf(acc[rt][0][r]);
            k[(size_t)row * HD + col] = f2bf(acc[rt][1][r]);
        }
        int row = rb + quad * 4;
        int b_ = row >> 11, sb = row & (SS - 1);
        ushort4 pk;
        pk.x = f2bf(acc[rt][2][0]); pk.y = f2bf(acc[rt][2][1]);
        pk.z = f2bf(acc[rt][2][2]); pk.w = f2bf(acc[rt][2][3]);
        *(ushort4*)(vT + ((size_t)b_ * HD + col) * SS + sb) = pk;
    }
}

// Split-K attention (R12-proven, unchanged): 128-row q-items, direct blockIdx
// mapping. Item = (b, Q, cx): 128 q-rows x one 256-key chunk; each wave owns
// 32 rows (2 row-tiles).
__global__ __launch_bounds__(256, 3) void attn_kernel(
    const unsigned short* __restrict__ q,
    const unsigned short* __restrict__ k,
    const unsigned short* __restrict__ vT,
    const int* __restrict__ mask,
    unsigned short* __restrict__ po,   // [B][32 qb][NCH][64 rows][64 d] bf16
    float* __restrict__ pl,            // [B][32 qb][NCH][64 rows] fp32
    float* __restrict__ out) {
    __shared__ __align__(16) unsigned short Ks[2][64 * TST];
    __shared__ __align__(16) unsigned short Vs[2][64 * TST];
    __shared__ __align__(16) unsigned short Ps[4][16 * PST];
    const int tid = threadIdx.x;
    const int lane = tid & 63, wave = tid >> 6;
    const int c = lane & 15, quad = lane >> 4;

    int t = NITEMS - 1 - blockIdx.x;       // big items first (low blockIdx)
    const int b_ = t / 72;
    int r = t % 72;
    int g = 0;
    while ((g + 1) * (g + 2) <= r) ++g;    // group: Q in {2g,2g+1}, nch=g+1
    int rr = r - g * (g + 1);
    const int Q = 2 * g + rr / (g + 1);
    const int cx = rr % (g + 1);
    const int kstart = cx * CHUNK;
    const int kend = min(kstart + CHUNK, Q * 128 + 128);
    const int ntiles = (kend - kstart) >> 6;   // 1..4 whole tiles
    const int nch_active = Q / 2 + 1;
    const int r0 = Q * 128 + wave * 32;        // this wave's first row

    const unsigned short* qb_p = q + (size_t)b_ * SS * HD;
    const unsigned short* kb_p = k + (size_t)b_ * SS * HD;
    const unsigned short* vb = vT + (size_t)b_ * HD * SS;
    const int* mb = mask + b_ * SS;

    bf16x8 aq[2][2];
#pragma unroll
    for (int rt = 0; rt < 2; ++rt) {
        const unsigned short* qrow = qb_p + (size_t)(r0 + rt * 16 + c) * HD + quad * 8;
        aq[rt][0] = *(const bf16x8*)(qrow);
        aq[rt][1] = *(const bf16x8*)(qrow + 32);
    }

    f32x4 o[2][4];
    float l_i[2][4];
#pragma unroll
    for (int rt = 0; rt < 2; ++rt)
        for (int tt = 0; tt < 4; ++tt) {
            o[rt][tt] = (f32x4){0.f, 0.f, 0.f, 0.f};
            l_i[rt][tt] = 0.f;
        }

    auto stage = [&](int buf, int k0) {
        const unsigned short* ksrc = kb_p + (size_t)k0 * HD;
        unsigned short* kd = &Ks[buf][0];
        unsigned short* vd = &Vs[buf][0];
#pragma unroll
        for (int rnd = 0; rnd < 2; ++rnd) {
            int e = (rnd * 256 + tid) * 8;
            int krow = e >> 6, kcol = e & 63;
            *(bf16x8*)(kd + krow * TST + kcol) = *(const bf16x8*)(ksrc + e);
            int t8 = rnd * 256 + tid;
            int vr = t8 >> 3, vc = (t8 & 7) * 8;
            *(bf16x8*)(vd + vr * TST + vc) = *(const bf16x8*)(vb + (size_t)vr * SS + k0 + vc);
        }
    };

    stage(0, kstart);
    for (int kt = 0; kt < ntiles; ++kt) {
        __syncthreads();
        const unsigned short* ks = &Ks[kt & 1][0];
        const unsigned short* vs = &Vs[kt & 1][0];
        const int k0 = kstart + kt * KT;
        bf16x8 kf[4][2];
#pragma unroll
        for (int kg = 0; kg < 4; ++kg) {
            kf[kg][0] = *(const bf16x8*)(ks + (kg * 16 + c) * TST + quad * 8);
            kf[kg][1] = *(const bf16x8*)(ks + (kg * 16 + c) * TST + 32 + quad * 8);
        }
        if (kt + 1 < ntiles) stage((kt + 1) & 1, k0 + KT);
#pragma unroll
        for (int rt = 0; rt < 2; ++rt) {
            const int rbase = r0 + rt * 16;
            const bool fullc = (k0 + KT <= rbase);
            float p[4][4];
#pragma unroll
            for (int kg = 0; kg < 4; ++kg) {
                f32x4 accs = (f32x4){0.f, 0.f, 0.f, 0.f};
                accs = __builtin_amdgcn_mfma_f32_16x16x32_bf16(aq[rt][0], kf[kg][0], accs, 0, 0, 0);
                accs = __builtin_amdgcn_mfma_f32_16x16x32_bf16(aq[rt][1], kf[kg][1], accs, 0, 0, 0);
                int key = k0 + kg * 16 + c;
                bool mk = (mb[key] != 0);
                for (int rr2 = 0; rr2 < 4; ++rr2) {
                    int row = rbase + quad * 4 + rr2;
                    bool keep = mk && (fullc || key <= row);
                    float e = __expf(fminf(accs[rr2], 80.f));  // scale folded into q
                    float pe = keep ? e : 0.f;
                    p[kg][rr2] = pe;
                    l_i[rt][rr2] += pe;
                }
            }
            unsigned short* pbuf = &Ps[wave][0];
#pragma unroll
            for (int kg = 0; kg < 4; ++kg)
                for (int rr2 = 0; rr2 < 4; ++rr2)
                    pbuf[(quad * 4 + rr2) * PST + kg * 16 + c] = f2bf_trunc(p[kg][rr2]);
            bf16x8 pa0 = *(const bf16x8*)(pbuf + c * PST + quad * 8);
            bf16x8 pa1 = *(const bf16x8*)(pbuf + c * PST + 32 + quad * 8);
#pragma unroll
            for (int tt = 0; tt < 4; ++tt) {
                bf16x8 bv0 = *(const bf16x8*)(vs + (tt * 16 + c) * TST + quad * 8);
                bf16x8 bv1 = *(const bf16x8*)(vs + (tt * 16 + c) * TST + 32 + quad * 8);
                o[rt][tt] = __builtin_amdgcn_mfma_f32_16x16x32_bf16(pa0, bv0, o[rt][tt], 0, 0, 0);
                o[rt][tt] = __builtin_amdgcn_mfma_f32_16x16x32_bf16(pa1, bv1, o[rt][tt], 0, 0, 0);
            }
        }
    }

#pragma unroll
    for (int rt = 0; rt < 2; ++rt)
        for (int rr2 = 0; rr2 < 4; ++rr2) {
            float s = l_i[rt][rr2];
            s += __shfl_xor(s, 1);
            s += __shfl_xor(s, 2);
            s += __shfl_xor(s, 4);
            s += __shfl_xor(s, 8);
            l_i[rt][rr2] = s;
        }

    if (nch_active == 1) {
        // rows < 256: sole chunk, final output directly
#pragma unroll
        for (int rt = 0; rt < 2; ++rt)
            for (int rr2 = 0; rr2 < 4; ++rr2) {
                int row = r0 + rt * 16 + quad * 4 + rr2;
                float l = l_i[rt][rr2];
                float inv = (l > 0.f) ? 1.f / l : 0.f;
                for (int tt = 0; tt < 4; ++tt)
                    out[((size_t)b_ * SS + row) * HD + tt * 16 + c] = o[rt][tt][rr2] * inv;
            }
        return;
    }

#pragma unroll
    for (int rt = 0; rt < 2; ++rt)
        for (int rr2 = 0; rr2 < 4; ++rr2) {
            int row_abs = r0 + rt * 16 + quad * 4 + rr2;
            int qb_i = row_abs >> 6, rl = row_abs & 63;
            size_t base = (size_t)(b_ * 32 + qb_i) * NCH + cx;
            float l = l_i[rt][rr2];
            float inv = (l > 0.f) ? 1.f / l : 0.f;
            for (int tt = 0; tt < 4; ++tt)
                po[base * 4096 + (size_t)rl * 64 + tt * 16 + c] = f2bf(o[rt][tt][rr2] * inv);
            if (c == 0) pl[base * 64 + rl] = l;
        }
}

// Combine rows >= 256 only: out = sum_c l_c * o_c / sum_c l_c.
__global__ __launch_bounds__(256) void combine_kernel(
    const unsigned short* __restrict__ po,
    const float* __restrict__ pl,
    float* __restrict__ out) {
    int t = blockIdx.x * 256 + threadIdx.x;
    if (t >= BB * (SS - 256) * HD) return;
    int d = t & 63;
    int rg = t >> 6;
    int b_ = rg / (SS - 256);
    int row = 256 + rg % (SS - 256);
    int qb = row >> 6, rl = row & 63;
    int nch = row / CHUNK + 1;
    size_t base = (size_t)(b_ * 32 + qb) * NCH;
    float L = 0.f, acc = 0.f;
    for (int c = 0; c < nch; ++c) {
        float l = pl[(base + c) * 64 + rl];
        L += l;
        acc += l * bf2f(po[(base + c) * 4096 + (size_t)rl * 64 + d]);
    }
    out[((size_t)b_ * SS + row) * HD + d] = (L > 0.f) ? acc / L : 0.f;
}

extern "C" void kernel_launch(void* const* d_in, const int* in_sizes, int n_in,
                              void* d_out, int out_size, void* d_ws, size_t ws_size,
                              hipStream_t stream) {
    const float* x = (const float*)d_in[0];
    const float* Wq = (const float*)d_in[1];
    const float* Wk = (const float*)d_in[2];
    const float* Wv = (const float*)d_in[3];
    const int* mask = (const int*)d_in[4];
    float* out = (float*)d_out;

    // ws: Wt[98304] | q,k,vT[3x1048576] bf16 | po bf16 | pl fp32 | flags[NPACK]
    unsigned short* ws = (unsigned short*)d_ws;
    unsigned short* Wt = ws;
    unsigned short* q = Wt + 3 * EE * HD;
    unsigned short* kk = q + (size_t)BB * SS * HD;
    unsigned short* vT = kk + (size_t)BB * SS * HD;
    unsigned short* po = vT + (size_t)BB * SS * HD;
    float* pl = (float*)(po + (size_t)BB * 32 * NCH * 4096);
    int* flags = (int*)(pl + (size_t)BB * 32 * NCH * 64);

    qkv_kernel<<<dim3(NPACK + BB * SS / 32), dim3(256), 0, stream>>>(x, Wq, Wk, Wv, Wt, q, kk, vT, flags);
    attn_kernel<<<dim3(NITEMS), dim3(256), 0, stream>>>(q, kk, vT, mask, po, pl, out);
    combine_kernel<<<dim3((BB * (SS - 256) * HD + 255) / 256), dim3(256), 0, stream>>>(po, pl, out);
}